// Round 8
// baseline (197.685 us; speedup 1.0000x reference)
//
#include <hip/hip_runtime.h>
#include <math.h>

// Problem constants (B, N, H, DM) = (2, 128, 2, 512), DK = 256
#define BB 2
#define NN 128
#define HH 2
#define DMM 512
#define DKK 256

typedef unsigned short u16;
typedef unsigned int u32;

// Partial-output layout inside each of P0/P1 (floats):
//   Q at 0, K at 131072, V at 262144, BX at 393216, total 458752
#define POFF_Q  0
#define POFF_K  131072
#define POFF_V  262144
#define POFF_BX 393216
#define PSIZE   458752

// ---------------------------------------------------------------------------
// K1: tiled projections with split-K=2.
// Computes partial sums over k-half kh into P[kh]:
//   P[kh]{Q,K,V,BX}[row, n] = (kh==0 ? bias[n] : 0) + sum_{k in half} A[row,k]*W[k,n]
// Tile: 32 rows x 128 cols, TK=64; thread = 4x4 register tile.
// Grid: 224 blocks (= 2 k-halves x 112 tiles) x 256 threads.
// ---------------------------------------------------------------------------
__global__ __launch_bounds__(256) void proj_kernel(
    const float* __restrict__ q_in, const float* __restrict__ k_in,
    const float* __restrict__ v_in, const float* __restrict__ bx_in,
    const float* __restrict__ Wq, const float* __restrict__ bq,
    const float* __restrict__ Wk, const float* __restrict__ bk,
    const float* __restrict__ Wv, const float* __restrict__ bv,
    const float* __restrict__ Wb, const float* __restrict__ bb,
    float* __restrict__ P0, float* __restrict__ P1)
{
    int id = blockIdx.x;
    int kh   = id & 1;            // k-half
    int tile = id >> 1;           // 0..111

    const float *A, *W, *bias;
    int cols, local, off;
    if (tile < 32)      { A = q_in;  W = Wq; bias = bq; cols = 512; local = tile;      off = POFF_Q;  }
    else if (tile < 64) { A = k_in;  W = Wk; bias = bk; cols = 512; local = tile - 32; off = POFF_K;  }
    else if (tile < 96) { A = v_in;  W = Wv; bias = bv; cols = 512; local = tile - 64; off = POFF_V;  }
    else                { A = bx_in; W = Wb; bias = bb; cols = 256; local = tile - 96; off = POFF_BX; }

    int ntiles = cols >> 7;                  // 4 or 2 N-tiles
    int mt = local / ntiles, nt = local % ntiles;
    int row0 = mt * 32, n0 = nt * 128;
    float* outp = (kh ? P1 : P0) + off;
    int k0base = kh * 256;

    __shared__ float sA[64][33];             // [k][row], padded
    __shared__ float sW[64][128];            // [k][col]

    int tid = threadIdx.x;
    int rg = tid >> 5;                       // 0..7  -> rows 4*rg..+3
    int cg = tid & 31;                       // 0..31 -> cols 4*cg..+3

    float acc[4][4];
    if (kh == 0) {
        float4 bv4 = *(const float4*)(bias + n0 + 4 * cg);
#pragma unroll
        for (int r = 0; r < 4; r++) {
            acc[r][0] = bv4.x; acc[r][1] = bv4.y; acc[r][2] = bv4.z; acc[r][3] = bv4.w;
        }
    } else {
#pragma unroll
        for (int r = 0; r < 4; r++)
#pragma unroll
            for (int c = 0; c < 4; c++) acc[r][c] = 0.f;
    }

    for (int kc = 0; kc < 4; kc++) {
        int k0 = k0base + kc * 64;
        // stage A-tile (32 rows x 64 k) transposed into sA
#pragma unroll
        for (int s = 0; s < 2; s++) {
            int idx = tid + s * 256;         // 0..511
            int r = idx >> 4;                // 0..31
            int f4 = (idx & 15) * 4;         // 0..60
            float4 v = *(const float4*)(A + (row0 + r) * DMM + k0 + f4);
            sA[f4 + 0][r] = v.x; sA[f4 + 1][r] = v.y;
            sA[f4 + 2][r] = v.z; sA[f4 + 3][r] = v.w;
        }
        // stage W-tile (64 k x 128 cols)
#pragma unroll
        for (int s = 0; s < 8; s++) {
            int idx = tid + s * 256;         // 0..2047
            int kk = idx >> 5;               // 0..63
            int c4 = (idx & 31) * 4;         // 0..124
            *(float4*)&sW[kk][c4] = *(const float4*)(W + (k0 + kk) * cols + n0 + c4);
        }
        __syncthreads();

#pragma unroll 8
        for (int kk = 0; kk < 64; kk++) {
            float4 a4 = *(float4*)&sA[kk][4 * rg];
            float4 w4 = *(float4*)&sW[kk][4 * cg];
            acc[0][0] += a4.x * w4.x; acc[0][1] += a4.x * w4.y; acc[0][2] += a4.x * w4.z; acc[0][3] += a4.x * w4.w;
            acc[1][0] += a4.y * w4.x; acc[1][1] += a4.y * w4.y; acc[1][2] += a4.y * w4.z; acc[1][3] += a4.y * w4.w;
            acc[2][0] += a4.z * w4.x; acc[2][1] += a4.z * w4.y; acc[2][2] += a4.z * w4.z; acc[2][3] += a4.z * w4.w;
            acc[3][0] += a4.w * w4.x; acc[3][1] += a4.w * w4.y; acc[3][2] += a4.w * w4.z; acc[3][3] += a4.w * w4.w;
        }
        __syncthreads();
    }

#pragma unroll
    for (int r = 0; r < 4; r++) {
        float4 v; v.x = acc[r][0]; v.y = acc[r][1]; v.z = acc[r][2]; v.w = acc[r][3];
        *(float4*)(outp + (row0 + 4 * rg + r) * cols + n0 + 4 * cg) = v;
    }
}

// ---------------------------------------------------------------------------
// K2: per-(b,h) stats + softmax.  Reads Q/K/BX as P0+P1 partial sums.
//   m != i :  e_m = scale*(c_m - t_m) ;  m == i :  d_i = scale*(g_i - a_i)
// with t=q.k, a=bx.k, c=q.bx, g=bx.bx over DK.
// Grid: 4 blocks (b*H+h) of 128 threads.
// ---------------------------------------------------------------------------
__global__ __launch_bounds__(128) void attn_kernel(
    const float* __restrict__ P0, const float* __restrict__ P1,
    float* __restrict__ attn_out)
{
    int bh = blockIdx.x;          // 0..3
    int b = bh >> 1, h = bh & 1;
    __shared__ float sE[NN], sD[NN];
    int tid = threadIdx.x;        // 0..127

    {   // phase 1: per-token dots (float4, summing the two k-half partials)
        int j = tid;
        size_t qoff = (size_t)POFF_Q  + (b * NN + j) * DMM + h * DKK;
        size_t koff = (size_t)POFF_K  + (b * NN + j) * DMM + h * DKK;
        size_t xoff = (size_t)POFF_BX + (b * NN + j) * DKK;
        const float4* q0 = (const float4*)(P0 + qoff);
        const float4* q1 = (const float4*)(P1 + qoff);
        const float4* k0 = (const float4*)(P0 + koff);
        const float4* k1 = (const float4*)(P1 + koff);
        const float4* x0 = (const float4*)(P0 + xoff);
        const float4* x1 = (const float4*)(P1 + xoff);
        float t = 0.f, a = 0.f, c = 0.f, g = 0.f;
#pragma unroll 4
        for (int ci = 0; ci < DKK / 4; ci++) {
            float4 qa = q0[ci], qb = q1[ci];
            float4 ka = k0[ci], kb = k1[ci];
            float4 xa = x0[ci], xb = x1[ci];
            float4 qv, kv, xv;
            qv.x = qa.x + qb.x; qv.y = qa.y + qb.y; qv.z = qa.z + qb.z; qv.w = qa.w + qb.w;
            kv.x = ka.x + kb.x; kv.y = ka.y + kb.y; kv.z = ka.z + kb.z; kv.w = ka.w + kb.w;
            xv.x = xa.x + xb.x; xv.y = xa.y + xb.y; xv.z = xa.z + xb.z; xv.w = xa.w + xb.w;
            t += qv.x * kv.x + qv.y * kv.y + qv.z * kv.z + qv.w * kv.w;
            a += xv.x * kv.x + xv.y * kv.y + xv.z * kv.z + xv.w * kv.w;
            c += qv.x * xv.x + qv.y * xv.y + qv.z * xv.z + qv.w * xv.w;
            g += xv.x * xv.x + xv.y * xv.y + xv.z * xv.z + xv.w * xv.w;
        }
        const float scale = 1.0f / sqrtf((float)(NN * DKK));
        sE[j] = scale * (c - t);
        sD[j] = scale * (g - a);
    }
    __syncthreads();

    // phase 2: one softmax row per thread
    int i = tid;
    float di = sD[i];
    float mx = di;
    for (int m = 0; m < NN; m++) {
        float sc = (m == i) ? di : sE[m];
        mx = fmaxf(mx, sc);
    }
    float sum = 0.f;
    for (int m = 0; m < NN; m++) {
        float sc = (m == i) ? di : sE[m];
        sum += __expf(sc - mx);
    }
    float inv = 1.0f / sum;
    float* arow = attn_out + (bh * NN + i) * NN;
    for (int m = 0; m < NN; m++) {
        float sc = (m == i) ? di : sE[m];
        arow[m] = __expf(sc - mx) * inv;
    }
}

// ---------------------------------------------------------------------------
// K3 (vwdw2): per-(b,j2) output-GEMM factors into ws (the L2-bound Wo stream,
// kept at 256 blocks so Wo L2 traffic stays 256 MB):
//   VW [b,j2,o] = bo[o] + sum_c V(j0,c)*Wo[c,o] + V(j1,c)*Wo[DK+c,o]
//   DW0[b,j2,o] = sum_c (BX(j0,c)-V(j0,c))*Wo[c,o]
//   DW1[b,j2,o] = sum_c (BX(j1,c)-V(j1,c))*Wo[DK+c,o]
// Grid: 256 blocks of 256 threads; thread owns 2 adjacent o.
// ---------------------------------------------------------------------------
__global__ __launch_bounds__(256) void vwdw2_kernel(
    const float* __restrict__ P0, const float* __restrict__ P1,
    const float* __restrict__ Wo, const float* __restrict__ bo,
    float* __restrict__ VW, float* __restrict__ DW0, float* __restrict__ DW1)
{
    int blk = blockIdx.x;            // b*128 + j2
    int b = blk >> 7, j2 = blk & 127;
    int h = j2 >> 6;
    int jj = (j2 & 63) * 2;          // token j0 ; j1 = jj+1
    int tid = threadIdx.x;

    __shared__ float sv0[DKK], sv1[DKK], sx0[DKK], sx1[DKK];

    {
        size_t v0o = (size_t)POFF_V  + (b * NN + jj)     * DMM + h * DKK + tid;
        size_t v1o = (size_t)POFF_V  + (b * NN + jj + 1) * DMM + h * DKK + tid;
        size_t x0o = (size_t)POFF_BX + (b * NN + jj)     * DKK + tid;
        size_t x1o = (size_t)POFF_BX + (b * NN + jj + 1) * DKK + tid;
        sv0[tid] = P0[v0o] + P1[v0o];
        sv1[tid] = P0[v1o] + P1[v1o];
        sx0[tid] = P0[x0o] + P1[x0o];
        sx1[tid] = P0[x1o] + P1[x1o];
    }
    __syncthreads();

    int o0 = tid * 2;
    float2 bo2 = *(const float2*)(bo + o0);
    float avw0 = bo2.x, avw1 = bo2.y;
    float a00 = 0.f, a01 = 0.f, a10 = 0.f, a11 = 0.f;

#pragma unroll 4
    for (int c = 0; c < DKK; c++) {
        float2 wt = *(const float2*)(Wo + c * DMM + o0);           // top row
        float2 wb = *(const float2*)(Wo + (DKK + c) * DMM + o0);   // bottom row
        float v0c = sv0[c], v1c = sv1[c];
        float d0c = sx0[c] - v0c, d1c = sx1[c] - v1c;
        avw0 += v0c * wt.x + v1c * wb.x;
        avw1 += v0c * wt.y + v1c * wb.y;
        a00 += d0c * wt.x; a01 += d0c * wt.y;
        a10 += d1c * wb.x; a11 += d1c * wb.y;
    }

    float2 r;
    r.x = avw0; r.y = avw1; *(float2*)(VW  + blk * DMM + o0) = r;
    r.x = a00;  r.y = a01;  *(float2*)(DW0 + blk * DMM + o0) = r;
    r.x = a10;  r.y = a11;  *(float2*)(DW1 + blk * DMM + o0) = r;
}

// ---------------------------------------------------------------------------
// K4 (writer): the 67 MB streaming write at full occupancy.
//   out[b,i,j2,o] = VW[b,j2,o] + attn[b,h,i,j0]*DW0[b,j2,o]
//                              + attn[b,h,i,j1]*DW1[b,j2,o]
// Grid: 2048 blocks = 256 (b,j2) x 8 i-chunks of 16; 256 threads.
// Thread: half = tid>>7 picks i-parity, owns float4 at o0=4*(tid&127);
// factors loaded once, 8 float4 stores.
// ---------------------------------------------------------------------------
__global__ __launch_bounds__(256) void write_kernel(
    const float* __restrict__ VW, const float* __restrict__ DW0,
    const float* __restrict__ DW1, const float* __restrict__ attn,
    float* __restrict__ out)
{
    int blk = blockIdx.x;
    int ib = blk >> 3;               // b*128 + j2
    int ic = blk & 7;                // i-chunk
    int b = ib >> 7, j2 = ib & 127;
    int h = j2 >> 6;
    int jj = (j2 & 63) * 2;
    int bh = b * HH + h;
    int i0 = ic * 16;

    __shared__ float sa0[16], sa1[16];
    int tid = threadIdx.x;
    if (tid < 16)      sa0[tid]      = attn[(bh * NN + i0 + tid) * NN + jj];
    else if (tid < 32) sa1[tid - 16] = attn[(bh * NN + i0 + tid - 16) * NN + jj + 1];

    int half = tid >> 7;             // 0/1: i parity
    int o0 = 4 * (tid & 127);
    float4 vw4 = *(const float4*)(VW  + ib * DMM + o0);
    float4 d04 = *(const float4*)(DW0 + ib * DMM + o0);
    float4 d14 = *(const float4*)(DW1 + ib * DMM + o0);
    __syncthreads();

#pragma unroll
    for (int s = 0; s < 8; s++) {
        int il = 2 * s + half;       // 0..15
        float p0 = sa0[il], p1 = sa1[il];
        float4 r;
        r.x = vw4.x + p0 * d04.x + p1 * d14.x;
        r.y = vw4.y + p0 * d04.y + p1 * d14.y;
        r.z = vw4.z + p0 * d04.z + p1 * d14.z;
        r.w = vw4.w + p0 * d04.w + p1 * d14.w;
        *(float4*)(out + ((size_t)(b * NN + i0 + il) * NN + j2) * DMM + o0) = r;
    }
}

// ---------------------------------------------------------------------------
extern "C" void kernel_launch(void* const* d_in, const int* in_sizes, int n_in,
                              void* d_out, int out_size, void* d_ws, size_t ws_size,
                              hipStream_t stream)
{
    // Input-order detection (host-side, constant per session):
    // setup_inputs() dict order  -> in_sizes[1] == 131072 (key)   [confirmed]
    // jax-pytree sorted order    -> in_sizes[1] == 262144 (Wk)    [fallback]
    const float *query, *key, *value, *boxes;
    const float *Wq, *bq, *Wk, *bk, *Wv, *bv, *Wb, *bb, *Wo, *bo;
    if (in_sizes[1] == 262144) {
        Wb    = (const float*)d_in[0];
        Wk    = (const float*)d_in[1];
        Wo    = (const float*)d_in[2];
        Wq    = (const float*)d_in[3];
        Wv    = (const float*)d_in[4];
        bb    = (const float*)d_in[5];
        bk    = (const float*)d_in[6];
        bo    = (const float*)d_in[7];
        boxes = (const float*)d_in[8];
        bq    = (const float*)d_in[9];
        bv    = (const float*)d_in[10];
        key   = (const float*)d_in[11];
        query = (const float*)d_in[12];
        value = (const float*)d_in[13];
    } else {
        query = (const float*)d_in[0];
        key   = (const float*)d_in[1];
        value = (const float*)d_in[2];
        boxes = (const float*)d_in[3];
        Wq = (const float*)d_in[4];  bq = (const float*)d_in[5];
        Wk = (const float*)d_in[6];  bk = (const float*)d_in[7];
        Wv = (const float*)d_in[8];  bv = (const float*)d_in[9];
        Wb = (const float*)d_in[10]; bb = (const float*)d_in[11];
        Wo = (const float*)d_in[12]; bo = (const float*)d_in[13];
    }

    float* ws = (float*)d_ws;
    float* P0  = ws;                     // partial sums, k-half 0 (incl. bias)
    float* P1  = ws + PSIZE;             // partial sums, k-half 1
    float* VW  = ws + 2 * PSIZE;         // 256*512
    float* DW0 = VW + 131072;            // 256*512
    float* DW1 = DW0 + 131072;           // 256*512

    float* out = (float*)d_out;                          // (2,128,128,512) fp32
    float* attn_out = out + (size_t)BB * NN * NN * DMM;  // (2,2,128,128) fp32

    proj_kernel<<<224, 256, 0, stream>>>(query, key, value, boxes,
                                         Wq, bq, Wk, bk, Wv, bv, Wb, bb,
                                         P0, P1);
    attn_kernel<<<4, 128, 0, stream>>>(P0, P1, attn_out);
    vwdw2_kernel<<<256, 256, 0, stream>>>(P0, P1, Wo, bo, VW, DW0, DW1);
    write_kernel<<<2048, 256, 0, stream>>>(VW, DW0, DW1, attn_out, out);
}

// Round 9
// 153.816 us; speedup vs baseline: 1.2852x; 1.2852x over previous
//
#include <hip/hip_runtime.h>
#include <math.h>

// Problem constants (B, N, H, DM) = (2, 128, 2, 512), DK = 256
#define BB 2
#define NN 128
#define HH 2
#define DMM 512
#define DKK 256

typedef unsigned short u16;
typedef unsigned int u32;

// Partial-output layout inside each of P0/P1 (floats):
#define POFF_Q  0
#define POFF_K  131072
#define POFF_V  262144
#define POFF_BX 393216
#define PSIZE   458752

// ---------------------------------------------------------------------------
// K1: tiled projections with split-K=2.  (unchanged from R7)
// Grid: 224 blocks (= 2 k-halves x 112 tiles) x 256 threads.
// ---------------------------------------------------------------------------
__global__ __launch_bounds__(256) void proj_kernel(
    const float* __restrict__ q_in, const float* __restrict__ k_in,
    const float* __restrict__ v_in, const float* __restrict__ bx_in,
    const float* __restrict__ Wq, const float* __restrict__ bq,
    const float* __restrict__ Wk, const float* __restrict__ bk,
    const float* __restrict__ Wv, const float* __restrict__ bv,
    const float* __restrict__ Wb, const float* __restrict__ bb,
    float* __restrict__ P0, float* __restrict__ P1)
{
    int id = blockIdx.x;
    int kh   = id & 1;            // k-half
    int tile = id >> 1;           // 0..111

    const float *A, *W, *bias;
    int cols, local, off;
    if (tile < 32)      { A = q_in;  W = Wq; bias = bq; cols = 512; local = tile;      off = POFF_Q;  }
    else if (tile < 64) { A = k_in;  W = Wk; bias = bk; cols = 512; local = tile - 32; off = POFF_K;  }
    else if (tile < 96) { A = v_in;  W = Wv; bias = bv; cols = 512; local = tile - 64; off = POFF_V;  }
    else                { A = bx_in; W = Wb; bias = bb; cols = 256; local = tile - 96; off = POFF_BX; }

    int ntiles = cols >> 7;                  // 4 or 2 N-tiles
    int mt = local / ntiles, nt = local % ntiles;
    int row0 = mt * 32, n0 = nt * 128;
    float* outp = (kh ? P1 : P0) + off;
    int k0base = kh * 256;

    __shared__ float sA[64][33];             // [k][row], padded
    __shared__ float sW[64][128];            // [k][col]

    int tid = threadIdx.x;
    int rg = tid >> 5;                       // 0..7  -> rows 4*rg..+3
    int cg = tid & 31;                       // 0..31 -> cols 4*cg..+3

    float acc[4][4];
    if (kh == 0) {
        float4 bv4 = *(const float4*)(bias + n0 + 4 * cg);
#pragma unroll
        for (int r = 0; r < 4; r++) {
            acc[r][0] = bv4.x; acc[r][1] = bv4.y; acc[r][2] = bv4.z; acc[r][3] = bv4.w;
        }
    } else {
#pragma unroll
        for (int r = 0; r < 4; r++)
#pragma unroll
            for (int c = 0; c < 4; c++) acc[r][c] = 0.f;
    }

    for (int kc = 0; kc < 4; kc++) {
        int k0 = k0base + kc * 64;
#pragma unroll
        for (int s = 0; s < 2; s++) {
            int idx = tid + s * 256;         // 0..511
            int r = idx >> 4;                // 0..31
            int f4 = (idx & 15) * 4;         // 0..60
            float4 v = *(const float4*)(A + (row0 + r) * DMM + k0 + f4);
            sA[f4 + 0][r] = v.x; sA[f4 + 1][r] = v.y;
            sA[f4 + 2][r] = v.z; sA[f4 + 3][r] = v.w;
        }
#pragma unroll
        for (int s = 0; s < 8; s++) {
            int idx = tid + s * 256;         // 0..2047
            int kk = idx >> 5;               // 0..63
            int c4 = (idx & 31) * 4;         // 0..124
            *(float4*)&sW[kk][c4] = *(const float4*)(W + (k0 + kk) * cols + n0 + c4);
        }
        __syncthreads();

#pragma unroll 8
        for (int kk = 0; kk < 64; kk++) {
            float4 a4 = *(float4*)&sA[kk][4 * rg];
            float4 w4 = *(float4*)&sW[kk][4 * cg];
            acc[0][0] += a4.x * w4.x; acc[0][1] += a4.x * w4.y; acc[0][2] += a4.x * w4.z; acc[0][3] += a4.x * w4.w;
            acc[1][0] += a4.y * w4.x; acc[1][1] += a4.y * w4.y; acc[1][2] += a4.y * w4.z; acc[1][3] += a4.y * w4.w;
            acc[2][0] += a4.z * w4.x; acc[2][1] += a4.z * w4.y; acc[2][2] += a4.z * w4.z; acc[2][3] += a4.z * w4.w;
            acc[3][0] += a4.w * w4.x; acc[3][1] += a4.w * w4.y; acc[3][2] += a4.w * w4.z; acc[3][3] += a4.w * w4.w;
        }
        __syncthreads();
    }

#pragma unroll
    for (int r = 0; r < 4; r++) {
        float4 v; v.x = acc[r][0]; v.y = acc[r][1]; v.z = acc[r][2]; v.w = acc[r][3];
        *(float4*)(outp + (row0 + 4 * rg + r) * cols + n0 + 4 * cg) = v;
    }
}

// ---------------------------------------------------------------------------
// K2a (stats): one WAVE per (b,h,j).  Lane = column -> coalesced float4 loads.
//   t=q.k, a=bx.k, c=q.bx, g=bx.bx over DK (summing P0+P1 partials)
//   E[bh,j] = scale*(c-t) ; D[bh,j] = scale*(g-a)
// Grid: 128 blocks x 256 threads (4 waves) = 512 waves.
// ---------------------------------------------------------------------------
__global__ __launch_bounds__(256) void stats_kernel(
    const float* __restrict__ P0, const float* __restrict__ P1,
    float* __restrict__ E, float* __restrict__ D)
{
    int tid = threadIdx.x;
    int gw = blockIdx.x * 4 + (tid >> 6);   // global wave id 0..511
    int lane = tid & 63;
    int j = gw & 127;
    int bh = gw >> 7;                        // 0..3
    int b = bh >> 1, h = bh & 1;

    size_t qoff = (size_t)POFF_Q  + (b * NN + j) * DMM + h * DKK + lane * 4;
    size_t koff = (size_t)POFF_K  + (b * NN + j) * DMM + h * DKK + lane * 4;
    size_t xoff = (size_t)POFF_BX + (b * NN + j) * DKK + lane * 4;

    float4 qa = *(const float4*)(P0 + qoff), qb = *(const float4*)(P1 + qoff);
    float4 ka = *(const float4*)(P0 + koff), kb = *(const float4*)(P1 + koff);
    float4 xa = *(const float4*)(P0 + xoff), xb = *(const float4*)(P1 + xoff);
    float4 qv, kv, xv;
    qv.x = qa.x + qb.x; qv.y = qa.y + qb.y; qv.z = qa.z + qb.z; qv.w = qa.w + qb.w;
    kv.x = ka.x + kb.x; kv.y = ka.y + kb.y; kv.z = ka.z + kb.z; kv.w = ka.w + kb.w;
    xv.x = xa.x + xb.x; xv.y = xa.y + xb.y; xv.z = xa.z + xb.z; xv.w = xa.w + xb.w;

    float t = qv.x * kv.x + qv.y * kv.y + qv.z * kv.z + qv.w * kv.w;
    float a = xv.x * kv.x + xv.y * kv.y + xv.z * kv.z + xv.w * kv.w;
    float c = qv.x * xv.x + qv.y * xv.y + qv.z * xv.z + qv.w * xv.w;
    float g = xv.x * xv.x + xv.y * xv.y + xv.z * xv.z + xv.w * xv.w;

#pragma unroll
    for (int off = 32; off > 0; off >>= 1) {
        t += __shfl_xor(t, off);
        a += __shfl_xor(a, off);
        c += __shfl_xor(c, off);
        g += __shfl_xor(g, off);
    }
    if (lane == 0) {
        const float scale = 1.0f / sqrtf((float)(NN * DKK));
        E[bh * NN + j] = scale * (c - t);
        D[bh * NN + j] = scale * (g - a);
    }
}

// ---------------------------------------------------------------------------
// K2b (softmax): one BLOCK per attn row (bh,i).  Thread = column -> coalesced.
//   sc_m = (m==i) ? D[i] : E[m];  attn[bh,i,m] = softmax_m(sc)
// Grid: 512 blocks x 128 threads (2 waves).
// ---------------------------------------------------------------------------
__global__ __launch_bounds__(128) void softmax_kernel(
    const float* __restrict__ E, const float* __restrict__ D,
    float* __restrict__ attn_out)
{
    int row = blockIdx.x;            // bh*128 + i
    int bh = row >> 7, i = row & 127;
    int m = threadIdx.x;             // column

    float e = E[bh * NN + m];
    float d = D[bh * NN + i];
    float sc = (m == i) ? d : e;

    __shared__ float redA[2], redB[2];

    float v = sc;
#pragma unroll
    for (int off = 32; off > 0; off >>= 1) v = fmaxf(v, __shfl_xor(v, off));
    if ((m & 63) == 0) redA[m >> 6] = v;
    __syncthreads();
    float mx = fmaxf(redA[0], redA[1]);

    float p = __expf(sc - mx);
    float s = p;
#pragma unroll
    for (int off = 32; off > 0; off >>= 1) s += __shfl_xor(s, off);
    if ((m & 63) == 0) redB[m >> 6] = s;
    __syncthreads();
    float inv = 1.0f / (redB[0] + redB[1]);

    attn_out[(size_t)row * NN + m] = p * inv;
}

// ---------------------------------------------------------------------------
// K3 (vwdw2): per-(b,j2) output-GEMM factors into ws.  (unchanged from R7)
// Grid: 256 blocks of 256 threads; thread owns 2 adjacent o.
// ---------------------------------------------------------------------------
__global__ __launch_bounds__(256) void vwdw2_kernel(
    const float* __restrict__ P0, const float* __restrict__ P1,
    const float* __restrict__ Wo, const float* __restrict__ bo,
    float* __restrict__ VW, float* __restrict__ DW0, float* __restrict__ DW1)
{
    int blk = blockIdx.x;            // b*128 + j2
    int b = blk >> 7, j2 = blk & 127;
    int h = j2 >> 6;
    int jj = (j2 & 63) * 2;          // token j0 ; j1 = jj+1
    int tid = threadIdx.x;

    __shared__ float sv0[DKK], sv1[DKK], sx0[DKK], sx1[DKK];

    {
        size_t v0o = (size_t)POFF_V  + (b * NN + jj)     * DMM + h * DKK + tid;
        size_t v1o = (size_t)POFF_V  + (b * NN + jj + 1) * DMM + h * DKK + tid;
        size_t x0o = (size_t)POFF_BX + (b * NN + jj)     * DKK + tid;
        size_t x1o = (size_t)POFF_BX + (b * NN + jj + 1) * DKK + tid;
        sv0[tid] = P0[v0o] + P1[v0o];
        sv1[tid] = P0[v1o] + P1[v1o];
        sx0[tid] = P0[x0o] + P1[x0o];
        sx1[tid] = P0[x1o] + P1[x1o];
    }
    __syncthreads();

    int o0 = tid * 2;
    float2 bo2 = *(const float2*)(bo + o0);
    float avw0 = bo2.x, avw1 = bo2.y;
    float a00 = 0.f, a01 = 0.f, a10 = 0.f, a11 = 0.f;

#pragma unroll 4
    for (int c = 0; c < DKK; c++) {
        float2 wt = *(const float2*)(Wo + c * DMM + o0);           // top row
        float2 wb = *(const float2*)(Wo + (DKK + c) * DMM + o0);   // bottom row
        float v0c = sv0[c], v1c = sv1[c];
        float d0c = sx0[c] - v0c, d1c = sx1[c] - v1c;
        avw0 += v0c * wt.x + v1c * wb.x;
        avw1 += v0c * wt.y + v1c * wb.y;
        a00 += d0c * wt.x; a01 += d0c * wt.y;
        a10 += d1c * wb.x; a11 += d1c * wb.y;
    }

    float2 r;
    r.x = avw0; r.y = avw1; *(float2*)(VW  + blk * DMM + o0) = r;
    r.x = a00;  r.y = a01;  *(float2*)(DW0 + blk * DMM + o0) = r;
    r.x = a10;  r.y = a11;  *(float2*)(DW1 + blk * DMM + o0) = r;
}

// ---------------------------------------------------------------------------
// K4 (writer): the 67 MB streaming write at full occupancy.  (unchanged)
// Grid: 2048 blocks = 256 (b,j2) x 8 i-chunks of 16; 256 threads.
// ---------------------------------------------------------------------------
__global__ __launch_bounds__(256) void write_kernel(
    const float* __restrict__ VW, const float* __restrict__ DW0,
    const float* __restrict__ DW1, const float* __restrict__ attn,
    float* __restrict__ out)
{
    int blk = blockIdx.x;
    int ib = blk >> 3;               // b*128 + j2
    int ic = blk & 7;                // i-chunk
    int b = ib >> 7, j2 = ib & 127;
    int h = j2 >> 6;
    int jj = (j2 & 63) * 2;
    int bh = b * HH + h;
    int i0 = ic * 16;

    __shared__ float sa0[16], sa1[16];
    int tid = threadIdx.x;
    if (tid < 16)      sa0[tid]      = attn[(bh * NN + i0 + tid) * NN + jj];
    else if (tid < 32) sa1[tid - 16] = attn[(bh * NN + i0 + tid - 16) * NN + jj + 1];

    int half = tid >> 7;             // 0/1: i parity
    int o0 = 4 * (tid & 127);
    float4 vw4 = *(const float4*)(VW  + ib * DMM + o0);
    float4 d04 = *(const float4*)(DW0 + ib * DMM + o0);
    float4 d14 = *(const float4*)(DW1 + ib * DMM + o0);
    __syncthreads();

#pragma unroll
    for (int s = 0; s < 8; s++) {
        int il = 2 * s + half;       // 0..15
        float p0 = sa0[il], p1 = sa1[il];
        float4 r;
        r.x = vw4.x + p0 * d04.x + p1 * d14.x;
        r.y = vw4.y + p0 * d04.y + p1 * d14.y;
        r.z = vw4.z + p0 * d04.z + p1 * d14.z;
        r.w = vw4.w + p0 * d04.w + p1 * d14.w;
        *(float4*)(out + ((size_t)(b * NN + i0 + il) * NN + j2) * DMM + o0) = r;
    }
}

// ---------------------------------------------------------------------------
extern "C" void kernel_launch(void* const* d_in, const int* in_sizes, int n_in,
                              void* d_out, int out_size, void* d_ws, size_t ws_size,
                              hipStream_t stream)
{
    // Input-order detection (host-side, constant per session):
    // setup_inputs() dict order  -> in_sizes[1] == 131072 (key)   [confirmed]
    const float *query, *key, *value, *boxes;
    const float *Wq, *bq, *Wk, *bk, *Wv, *bv, *Wb, *bb, *Wo, *bo;
    if (in_sizes[1] == 262144) {
        Wb    = (const float*)d_in[0];
        Wk    = (const float*)d_in[1];
        Wo    = (const float*)d_in[2];
        Wq    = (const float*)d_in[3];
        Wv    = (const float*)d_in[4];
        bb    = (const float*)d_in[5];
        bk    = (const float*)d_in[6];
        bo    = (const float*)d_in[7];
        boxes = (const float*)d_in[8];
        bq    = (const float*)d_in[9];
        bv    = (const float*)d_in[10];
        key   = (const float*)d_in[11];
        query = (const float*)d_in[12];
        value = (const float*)d_in[13];
    } else {
        query = (const float*)d_in[0];
        key   = (const float*)d_in[1];
        value = (const float*)d_in[2];
        boxes = (const float*)d_in[3];
        Wq = (const float*)d_in[4];  bq = (const float*)d_in[5];
        Wk = (const float*)d_in[6];  bk = (const float*)d_in[7];
        Wv = (const float*)d_in[8];  bv = (const float*)d_in[9];
        Wb = (const float*)d_in[10]; bb = (const float*)d_in[11];
        Wo = (const float*)d_in[12]; bo = (const float*)d_in[13];
    }

    float* ws = (float*)d_ws;
    float* P0  = ws;                     // partial sums, k-half 0 (incl. bias)
    float* P1  = ws + PSIZE;             // partial sums, k-half 1
    float* VW  = ws + 2 * PSIZE;         // 256*512
    float* DW0 = VW + 131072;            // 256*512
    float* DW1 = DW0 + 131072;           // 256*512
    float* E   = DW1 + 131072;           // 4*128
    float* D   = E + 512;                // 4*128

    float* out = (float*)d_out;                          // (2,128,128,512) fp32
    float* attn_out = out + (size_t)BB * NN * NN * DMM;  // (2,2,128,128) fp32

    proj_kernel<<<224, 256, 0, stream>>>(query, key, value, boxes,
                                         Wq, bq, Wk, bk, Wv, bv, Wb, bb,
                                         P0, P1);
    stats_kernel<<<128, 256, 0, stream>>>(P0, P1, E, D);
    softmax_kernel<<<512, 128, 0, stream>>>(E, D, attn_out);
    vwdw2_kernel<<<256, 256, 0, stream>>>(P0, P1, Wo, bo, VW, DW0, DW1);
    write_kernel<<<2048, 256, 0, stream>>>(VW, DW0, DW1, attn_out, out);
}